// Round 5
// baseline (201.032 us; speedup 1.0000x reference)
//
#include <hip/hip_runtime.h>
#include <cstddef>

#define BATCH 8
#define NN 1024
#define IN_DIM 768
#define OUT_DIM 96
#define HEADS 8
#define M_ROWS 8192
#define NCOLS 1536

typedef __attribute__((ext_vector_type(8))) short short8;
typedef __attribute__((ext_vector_type(4))) float f32x4;
typedef __attribute__((ext_vector_type(4))) unsigned short ushort4v;

typedef __attribute__((address_space(1))) void gvoid_t;
typedef __attribute__((address_space(3))) void lvoid_t;

// async global->LDS, 16B per lane; lds dest = wave-uniform base + lane*16
__device__ __forceinline__ void gload_lds16(const void* g, void* l) {
    __builtin_amdgcn_global_load_lds((gvoid_t*)(unsigned long long)g,
                                     (lvoid_t*)(unsigned int)(unsigned long long)l,
                                     16, 0, 0);
}

__device__ __forceinline__ unsigned short f2bf(float x) {
    unsigned int u = __builtin_bit_cast(unsigned int, x);
    u += 0x7fffu + ((u >> 16) & 1u);          // RTNE
    return (unsigned short)(u >> 16);
}
__device__ __forceinline__ float bf2f(unsigned short u) {
    unsigned int v = ((unsigned int)u) << 16;
    return __builtin_bit_cast(float, v);
}
__device__ __forceinline__ float tanh_fast(float x) {
    return 1.f - 2.f / (__expf(2.f * x) + 1.f);
}

// ---------- convert feat_in -> bf16 ----------
__global__ void xb_kernel(const float* __restrict__ x, unsigned short* __restrict__ xb) {
    int idx = blockIdx.x * 256 + threadIdx.x;
    const float4* p = (const float4*)(x + (size_t)idx * 8);
    float4 a = p[0], b = p[1];
    short8 r;
    r[0] = (short)f2bf(a.x); r[1] = (short)f2bf(a.y); r[2] = (short)f2bf(a.z); r[3] = (short)f2bf(a.w);
    r[4] = (short)f2bf(b.x); r[5] = (short)f2bf(b.y); r[6] = (short)f2bf(b.z); r[7] = (short)f2bf(b.w);
    *(short8*)(xb + (size_t)idx * 8) = r;
}

// ---------- pack W and Hw into BcatT[c][k] bf16 ----------
__global__ void pack_w_kernel(const float* __restrict__ W, unsigned short* __restrict__ BT) {
    int idx = blockIdx.x * 256 + threadIdx.x;
    int c = idx / IN_DIM, i = idx % IN_DIM;
    int h = c / OUT_DIM, o = c % OUT_DIM;
    BT[(size_t)c * IN_DIM + i] = f2bf(W[((size_t)h * IN_DIM + i) * OUT_DIM + o]);
}
__global__ void pack_hw_kernel(const float* __restrict__ Hw, unsigned short* __restrict__ BT) {
    int idx = blockIdx.x * 256 + threadIdx.x;
    int c = idx / IN_DIM, i = idx % IN_DIM;
    BT[(size_t)(768 + c) * IN_DIM + i] = f2bf(Hw[(size_t)c * IN_DIM + i]);
}

// ---------- GEMM1: Xb[8192,768] @ BT^T -> h_bt (bf16 [bh][o][n]) + gate (f16) ----------
__global__ __launch_bounds__(256) void gemm1_kernel(
        const unsigned short* __restrict__ Xb, const unsigned short* __restrict__ BT,
        const float* __restrict__ Hb,
        unsigned short* __restrict__ h_bt, unsigned short* __restrict__ gate) {
    __shared__ __align__(16) unsigned short As[128 * 64];
    __shared__ __align__(16) unsigned short Bs[128 * 64];
    __shared__ float hbs[128];
    int m0 = blockIdx.x * 128;
    int c0 = blockIdx.y * 128;
    int t = threadIdx.x;
    int w = t >> 6, lane = t & 63, l15 = t & 15, quad = lane >> 4;
    if (c0 >= 768 && t < 128) hbs[t] = Hb[c0 - 768 + t];
    f32x4 acc[2][8] = {};
    for (int k0 = 0; k0 < IN_DIM; k0 += 64) {
        __syncthreads();
        #pragma unroll
        for (int cc = 0; cc < 4; ++cc) {
            int base64 = (w * 4 + cc) * 64;          // wave-uniform chunk base
            int p = base64 + lane;
            int r = p >> 3, qs = p & 7;
            int qb = qs ^ (r & 7);                   // inverse of read-side swizzle
            gload_lds16(Xb + (size_t)(m0 + r) * IN_DIM + k0 + qb * 8, As + base64 * 8);
            gload_lds16(BT + (size_t)(c0 + r) * IN_DIM + k0 + qb * 8, Bs + base64 * 8);
        }
        __syncthreads();
        #pragma unroll
        for (int ks = 0; ks < 2; ++ks) {
            short8 af[2], bfr[8];
            #pragma unroll
            for (int mt = 0; mt < 2; ++mt) {
                int r = w * 32 + mt * 16 + l15;
                int cb = (ks * 4 + quad) ^ (r & 7);
                af[mt] = *(const short8*)(As + r * 64 + cb * 8);
            }
            #pragma unroll
            for (int nt = 0; nt < 8; ++nt) {
                int r = nt * 16 + l15;
                int cb = (ks * 4 + quad) ^ (r & 7);
                bfr[nt] = *(const short8*)(Bs + r * 64 + cb * 8);
            }
            #pragma unroll
            for (int mt = 0; mt < 2; ++mt)
                #pragma unroll
                for (int nt = 0; nt < 8; ++nt)
                    acc[mt][nt] = __builtin_amdgcn_mfma_f32_16x16x32_bf16(af[mt], bfr[nt], acc[mt][nt], 0, 0, 0);
        }
    }
    int b = m0 >> 10;
    #pragma unroll
    for (int mt = 0; mt < 2; ++mt) {
        int rowbase = m0 + w * 32 + mt * 16 + quad * 4;
        int nbase = rowbase & 1023;
        #pragma unroll
        for (int nt = 0; nt < 8; ++nt) {
            int c = c0 + nt * 16 + l15;
            if (c < 768) {
                int hh = c / OUT_DIM, o = c % OUT_DIM;
                ushort4v hb;
                hb[0] = f2bf(acc[mt][nt][0]); hb[1] = f2bf(acc[mt][nt][1]);
                hb[2] = f2bf(acc[mt][nt][2]); hb[3] = f2bf(acc[mt][nt][3]);
                *(ushort4v*)(h_bt + ((size_t)(b * 8 + hh) * OUT_DIM + o) * NN + nbase) = hb;
            } else {
                int cl = nt * 16 + l15;                // local col in [0,128)
                int cg = c - 768;
                #pragma unroll
                for (int reg = 0; reg < 4; ++reg) {
                    float z = acc[mt][nt][reg] + hbs[cl];
                    float g = __builtin_amdgcn_rcpf(1.f + __builtin_amdgcn_exp2f(-1.44269504f * z));
                    _Float16 gh = (_Float16)g;
                    gate[(size_t)(rowbase + reg) * 768 + cg] = __builtin_bit_cast(unsigned short, gh);
                }
            }
        }
    }
}

// ---------- a_src/a_dst from bf16 h_bt (pre-scaled by log2(e)) ----------
__global__ __launch_bounds__(256) void a_kernel(const unsigned short* __restrict__ h_bt,
                                                const float* __restrict__ w_src,
                                                const float* __restrict__ w_dst,
                                                float* __restrict__ a_src, float* __restrict__ a_dst) {
    __shared__ unsigned short ht[96 * 72];
    __shared__ float ws_s[96], wd_s[96];
    __shared__ float pps[4][64], ppd[4][64];
    int bh = blockIdx.x >> 4;
    int n0 = (blockIdx.x & 15) * 64;
    int head = bh & 7;
    int t = threadIdx.x;
    if (t < 96) { ws_s[t] = w_src[head * 96 + t]; wd_s[t] = w_dst[head * 96 + t]; }
    for (int f = t; f < 768; f += 256) {
        int row = f >> 3, c8 = (f & 7) * 8;
        *(short8*)(ht + row * 72 + c8) = *(const short8*)(h_bt + ((size_t)bh * 96 + row) * NN + n0 + c8);
    }
    __syncthreads();
    int n = t & 63, part = t >> 6;
    float ps = 0.f, pd = 0.f;
    #pragma unroll
    for (int oo = 0; oo < 24; ++oo) {
        int o = part * 24 + oo;
        float th = tanh_fast(bf2f(ht[o * 72 + n]));
        ps += th * ws_s[o];
        pd += th * wd_s[o];
    }
    pps[part][n] = ps; ppd[part][n] = pd;
    __syncthreads();
    if (t < 64) {
        float s = pps[0][t] + pps[1][t] + pps[2][t] + pps[3][t];
        float d = ppd[0][t] + ppd[1][t] + ppd[2][t] + ppd[3][t];
        a_src[bh * 1024 + n0 + t] = s * 1.44269504f;    // log2(e) folded for exp2
        a_dst[bh * 1024 + n0 + t] = d * 1.44269504f;
    }
}

// ---------- attention + fused epilogue ----------
// Register-direct E build (A-fragment partition), inline adj read (single-pass),
// DMA double-buffered hs, one barrier per j-iter.
__global__ __launch_bounds__(256) void attn_kernel(
        const unsigned short* __restrict__ h_bt, const float* __restrict__ adj,
        const float* __restrict__ a_src_g, const float* __restrict__ a_dst_g,
        const unsigned short* __restrict__ gate, const unsigned short* __restrict__ Xb,
        const float* __restrict__ bias, float* __restrict__ out) {
    __shared__ __align__(16) unsigned short hs[2][96 * 64];
    __shared__ __align__(16) float adst[1024];
    __shared__ float asrc[64];
    __shared__ float bias_s[96];
    int blk = blockIdx.x;
    int bh = blk >> 4, i0 = (blk & 15) * 64, b = bh >> 3, hh = bh & 7;
    int t = threadIdx.x;
    int w = t >> 6, lane = t & 63, l15 = t & 15, quad = lane >> 4;
    for (int q = 0; q < 4; ++q) adst[q * 256 + t] = a_dst_g[bh * 1024 + q * 256 + t];
    if (t < 96) bias_s[t] = bias[t];
    if (t >= 128 && t < 192) asrc[t - 128] = a_src_g[bh * 1024 + i0 + (t - 128)];
    const unsigned short* hhp = h_bt + (size_t)bh * 96 * NN;
    // DMA tile 0 into hs[0] (XOR-swizzled, lane-contiguous LDS dest)
    #pragma unroll
    for (int cc = 0; cc < 3; ++cc) {
        int u0 = (w * 3 + cc) * 64;
        int p = u0 + lane;
        int r = p >> 3, qs = p & 7, qb = qs ^ (r & 7);
        gload_lds16(hhp + (size_t)r * NN + qb * 8, (char*)&hs[0][0] + (size_t)u0 * 16);
    }
    int irow = i0 + w * 16 + l15;
    const float* arow = adj + ((size_t)b * NN + irow) * NN;
    float4 adjreg[4];
    #pragma unroll
    for (int ks = 0; ks < 2; ++ks) {
        adjreg[2 * ks]     = *(const float4*)(arow + ks * 32 + quad * 8);
        adjreg[2 * ks + 1] = *(const float4*)(arow + ks * 32 + quad * 8 + 4);
    }
    f32x4 acc[7] = {};
    short8 ones = {};
    if (l15 == 0) {
        #pragma unroll
        for (int u = 0; u < 8; ++u) ones[u] = (short)0x3F80;   // bf16 1.0
    }
    __syncthreads();
    float si = asrc[w * 16 + l15];
    for (int j0 = 0; j0 < 1024; j0 += 64) {
        int cur = (j0 >> 6) & 1;
        int jn = j0 + 64;
        // DMA next h tile into the other buffer (drained by the end-of-iter barrier)
        if (jn < 1024) {
            #pragma unroll
            for (int cc = 0; cc < 3; ++cc) {
                int u0 = (w * 3 + cc) * 64;
                int p = u0 + lane;
                int r = p >> 3, qs = p & 7, qb = qs ^ (r & 7);
                gload_lds16(hhp + (size_t)r * NN + jn + qb * 8, (char*)&hs[cur ^ 1][0] + (size_t)u0 * 16);
            }
        }
        // build A fragments in-register: lane owns E[i=w*16+l15][j=ks*32+quad*8+u]
        short8 af[2];
        #pragma unroll
        for (int ks = 0; ks < 2; ++ks) {
            f32x4 d0 = *(const f32x4*)(&adst[j0 + ks * 32 + quad * 8]);
            f32x4 d1 = *(const f32x4*)(&adst[j0 + ks * 32 + quad * 8 + 4]);
            float av[8] = {adjreg[2 * ks].x, adjreg[2 * ks].y, adjreg[2 * ks].z, adjreg[2 * ks].w,
                           adjreg[2 * ks + 1].x, adjreg[2 * ks + 1].y, adjreg[2 * ks + 1].z, adjreg[2 * ks + 1].w};
            float dv[8] = {d0[0], d0[1], d0[2], d0[3], d1[0], d1[1], d1[2], d1[3]};
            float ev[8];
            #pragma unroll
            for (int u = 0; u < 8; ++u) {
                float s = si + dv[u];
                float l = fmaxf(s, 0.2f * s);
                float e = __builtin_amdgcn_exp2f(l);
                ev[u] = (av[u] != 0.f) ? e : 0.f;
            }
            union { unsigned int u4[4]; short8 s8; } pk;
            #pragma unroll
            for (int p2 = 0; p2 < 4; ++p2) {
                unsigned int u0b = __builtin_bit_cast(unsigned int, ev[2 * p2]) + 0x8000u;
                unsigned int u1b = __builtin_bit_cast(unsigned int, ev[2 * p2 + 1]) + 0x8000u;
                pk.u4[p2] = __builtin_amdgcn_perm(u1b, u0b, 0x07060302);
            }
            af[ks] = pk.s8;
        }
        // prefetch adj for next iter (flies across the MFMA phase)
        if (jn < 1024) {
            #pragma unroll
            for (int ks = 0; ks < 2; ++ks) {
                adjreg[2 * ks]     = *(const float4*)(arow + jn + ks * 32 + quad * 8);
                adjreg[2 * ks + 1] = *(const float4*)(arow + jn + ks * 32 + quad * 8 + 4);
            }
        }
        // MFMA on current buffer
        #pragma unroll
        for (int ks = 0; ks < 2; ++ks) {
            #pragma unroll
            for (int nt = 0; nt < 6; ++nt) {
                int r = nt * 16 + l15;
                int qs = (ks * 4 + quad) ^ (r & 7);
                short8 bfr = *(const short8*)(&hs[cur][(size_t)(r * 8 + qs) * 8]);
                acc[nt] = __builtin_amdgcn_mfma_f32_16x16x32_bf16(af[ks], bfr, acc[nt], 0, 0, 0);
            }
            acc[6] = __builtin_amdgcn_mfma_f32_16x16x32_bf16(af[ks], ones, acc[6], 0, 0, 0);
        }
        __syncthreads();
    }
    // fused epilogue: bias + elu + precomputed f16 gate + bf16 x + blend -> out
    int rowq = i0 + w * 16 + quad * 4;
    #pragma unroll
    for (int reg = 0; reg < 4; ++reg) {
        float ssum = __shfl(acc[6][reg], (lane & 48));    // ones-column (n=0) holds row sum
        float inv = (ssum > 0.f) ? __builtin_amdgcn_rcpf(ssum) : 0.f;
        int n = rowq + reg;
        size_t mrow = ((size_t)b * NN + n) * 768 + hh * 96;
        #pragma unroll
        for (int nt = 0; nt < 6; ++nt) {
            int cl = nt * 16 + l15;
            float v = acc[nt][reg] * inv + bias_s[cl];
            float e = (v > 0.f) ? v : (__builtin_amdgcn_exp2f(v * 1.44269504f) - 1.f);
            _Float16 gh = __builtin_bit_cast(_Float16, gate[mrow + cl]);
            float g = (float)gh;
            float x = bf2f(Xb[mrow + cl]);
            out[mrow + cl] = x + g * (e - x);
        }
    }
}

extern "C" void kernel_launch(void* const* d_in, const int* in_sizes, int n_in,
                              void* d_out, int out_size, void* d_ws, size_t ws_size,
                              hipStream_t stream) {
    const float* feat_in = (const float*)d_in[0];
    const float* adj     = (const float*)d_in[1];
    const float* W       = (const float*)d_in[2];
    const float* bbias   = (const float*)d_in[3];
    const float* w_src   = (const float*)d_in[4];
    const float* w_dst   = (const float*)d_in[5];
    const float* Hw      = (const float*)d_in[6];
    const float* Hb      = (const float*)d_in[7];
    float* out = (float*)d_out;
    char* base = (char*)d_ws;

    unsigned short* Xb    = (unsigned short*)(base);                 // 12,582,912 B
    unsigned short* BcatT = (unsigned short*)(base + 12582912);      //  2,359,296 B
    unsigned short* h_bt  = (unsigned short*)(base + 14942208);      // 12,582,912 B
    unsigned short* gate  = (unsigned short*)(base + 27525120);      // 12,582,912 B (f16)
    float* a_src = (float*)(base + 40108032);                        //    262,144 B
    float* a_dst = (float*)(base + 40370176);                        //    262,144 B (end ~40.6 MB)

    xb_kernel<<<(M_ROWS * IN_DIM / 8) / 256, 256, 0, stream>>>(feat_in, Xb);
    pack_w_kernel<<<(768 * IN_DIM) / 256, 256, 0, stream>>>(W, BcatT);
    pack_hw_kernel<<<(768 * IN_DIM) / 256, 256, 0, stream>>>(Hw, BcatT);
    gemm1_kernel<<<dim3(M_ROWS / 128, NCOLS / 128), 256, 0, stream>>>(Xb, BcatT, Hb, h_bt, gate);
    a_kernel<<<64 * 16, 256, 0, stream>>>(h_bt, w_src, w_dst, a_src, a_dst);
    attn_kernel<<<64 * 16, 256, 0, stream>>>(h_bt, adj, a_src, a_dst, gate, Xb, bbias, out);
}

// Round 6
// 190.912 us; speedup vs baseline: 1.0530x; 1.0530x over previous
//
#include <hip/hip_runtime.h>
#include <cstddef>

#define BATCH 8
#define NN 1024
#define IN_DIM 768
#define OUT_DIM 96
#define HEADS 8
#define M_ROWS 8192
#define NCOLS 1536

typedef __attribute__((ext_vector_type(8))) short short8;
typedef __attribute__((ext_vector_type(4))) float f32x4;
typedef __attribute__((ext_vector_type(4))) unsigned short ushort4v;

typedef __attribute__((address_space(1))) void gvoid_t;
typedef __attribute__((address_space(3))) void lvoid_t;

// async global->LDS, 16B per lane; lds dest = wave-uniform base + lane*16
__device__ __forceinline__ void gload_lds16(const void* g, void* l) {
    __builtin_amdgcn_global_load_lds((gvoid_t*)(unsigned long long)g,
                                     (lvoid_t*)(unsigned int)(unsigned long long)l,
                                     16, 0, 0);
}

__device__ __forceinline__ unsigned short f2bf(float x) {
    unsigned int u = __builtin_bit_cast(unsigned int, x);
    u += 0x7fffu + ((u >> 16) & 1u);          // RTNE
    return (unsigned short)(u >> 16);
}
__device__ __forceinline__ float bf2f(unsigned short u) {
    unsigned int v = ((unsigned int)u) << 16;
    return __builtin_bit_cast(float, v);
}
__device__ __forceinline__ float tanh_fast(float x) {
    return 1.f - 2.f / (__expf(2.f * x) + 1.f);
}

// ---------- convert feat_in -> bf16 ----------
__global__ void xb_kernel(const float* __restrict__ x, unsigned short* __restrict__ xb) {
    int idx = blockIdx.x * 256 + threadIdx.x;
    const float4* p = (const float4*)(x + (size_t)idx * 8);
    float4 a = p[0], b = p[1];
    short8 r;
    r[0] = (short)f2bf(a.x); r[1] = (short)f2bf(a.y); r[2] = (short)f2bf(a.z); r[3] = (short)f2bf(a.w);
    r[4] = (short)f2bf(b.x); r[5] = (short)f2bf(b.y); r[6] = (short)f2bf(b.z); r[7] = (short)f2bf(b.w);
    *(short8*)(xb + (size_t)idx * 8) = r;
}

// ---------- pack W and Hw into BcatT[c][k] bf16 ----------
__global__ void pack_w_kernel(const float* __restrict__ W, unsigned short* __restrict__ BT) {
    int idx = blockIdx.x * 256 + threadIdx.x;
    int c = idx / IN_DIM, i = idx % IN_DIM;
    int h = c / OUT_DIM, o = c % OUT_DIM;
    BT[(size_t)c * IN_DIM + i] = f2bf(W[((size_t)h * IN_DIM + i) * OUT_DIM + o]);
}
__global__ void pack_hw_kernel(const float* __restrict__ Hw, unsigned short* __restrict__ BT) {
    int idx = blockIdx.x * 256 + threadIdx.x;
    int c = idx / IN_DIM, i = idx % IN_DIM;
    BT[(size_t)(768 + c) * IN_DIM + i] = f2bf(Hw[(size_t)c * IN_DIM + i]);
}

// ---------- pack adj -> bitmask (1 bit per edge) ----------
__global__ void pack_abits_kernel(const float* __restrict__ adj, unsigned int* __restrict__ abits) {
    int idx = blockIdx.x * 256 + threadIdx.x;   // 262144 words
    const float4* p = (const float4*)(adj + (size_t)idx * 32);
    unsigned int m = 0;
    #pragma unroll
    for (int q = 0; q < 8; ++q) {
        float4 v = p[q];
        m |= (v.x != 0.f ? 1u : 0u) << (q * 4 + 0);
        m |= (v.y != 0.f ? 1u : 0u) << (q * 4 + 1);
        m |= (v.z != 0.f ? 1u : 0u) << (q * 4 + 2);
        m |= (v.w != 0.f ? 1u : 0u) << (q * 4 + 3);
    }
    abits[idx] = m;
}

// ---------- GEMM1: Xb[8192,768] @ BT^T -> h_bt (bf16 [bh][o][n]) + gate (f16) ----------
__global__ __launch_bounds__(256) void gemm1_kernel(
        const unsigned short* __restrict__ Xb, const unsigned short* __restrict__ BT,
        const float* __restrict__ Hb,
        unsigned short* __restrict__ h_bt, unsigned short* __restrict__ gate) {
    __shared__ __align__(16) unsigned short As[128 * 64];
    __shared__ __align__(16) unsigned short Bs[128 * 64];
    __shared__ float hbs[128];
    int m0 = blockIdx.x * 128;
    int c0 = blockIdx.y * 128;
    int t = threadIdx.x;
    int w = t >> 6, lane = t & 63, l15 = t & 15, quad = lane >> 4;
    if (c0 >= 768 && t < 128) hbs[t] = Hb[c0 - 768 + t];
    f32x4 acc[2][8] = {};
    for (int k0 = 0; k0 < IN_DIM; k0 += 64) {
        __syncthreads();
        #pragma unroll
        for (int cc = 0; cc < 4; ++cc) {
            int base64 = (w * 4 + cc) * 64;          // wave-uniform chunk base
            int p = base64 + lane;
            int r = p >> 3, qs = p & 7;
            int qb = qs ^ (r & 7);                   // inverse of read-side swizzle
            gload_lds16(Xb + (size_t)(m0 + r) * IN_DIM + k0 + qb * 8, As + base64 * 8);
            gload_lds16(BT + (size_t)(c0 + r) * IN_DIM + k0 + qb * 8, Bs + base64 * 8);
        }
        __syncthreads();
        #pragma unroll
        for (int ks = 0; ks < 2; ++ks) {
            short8 af[2], bfr[8];
            #pragma unroll
            for (int mt = 0; mt < 2; ++mt) {
                int r = w * 32 + mt * 16 + l15;
                int cb = (ks * 4 + quad) ^ (r & 7);
                af[mt] = *(const short8*)(As + r * 64 + cb * 8);
            }
            #pragma unroll
            for (int nt = 0; nt < 8; ++nt) {
                int r = nt * 16 + l15;
                int cb = (ks * 4 + quad) ^ (r & 7);
                bfr[nt] = *(const short8*)(Bs + r * 64 + cb * 8);
            }
            #pragma unroll
            for (int mt = 0; mt < 2; ++mt)
                #pragma unroll
                for (int nt = 0; nt < 8; ++nt)
                    acc[mt][nt] = __builtin_amdgcn_mfma_f32_16x16x32_bf16(af[mt], bfr[nt], acc[mt][nt], 0, 0, 0);
        }
    }
    int b = m0 >> 10;
    #pragma unroll
    for (int mt = 0; mt < 2; ++mt) {
        int rowbase = m0 + w * 32 + mt * 16 + quad * 4;
        int nbase = rowbase & 1023;
        #pragma unroll
        for (int nt = 0; nt < 8; ++nt) {
            int c = c0 + nt * 16 + l15;
            if (c < 768) {
                int hh = c / OUT_DIM, o = c % OUT_DIM;
                ushort4v hb;
                hb[0] = f2bf(acc[mt][nt][0]); hb[1] = f2bf(acc[mt][nt][1]);
                hb[2] = f2bf(acc[mt][nt][2]); hb[3] = f2bf(acc[mt][nt][3]);
                *(ushort4v*)(h_bt + ((size_t)(b * 8 + hh) * OUT_DIM + o) * NN + nbase) = hb;
            } else {
                int cl = nt * 16 + l15;
                int cg = c - 768;
                #pragma unroll
                for (int reg = 0; reg < 4; ++reg) {
                    float z = acc[mt][nt][reg] + hbs[cl];
                    float g = __builtin_amdgcn_rcpf(1.f + __builtin_amdgcn_exp2f(-1.44269504f * z));
                    _Float16 gh = (_Float16)g;
                    gate[(size_t)(rowbase + reg) * 768 + cg] = __builtin_bit_cast(unsigned short, gh);
                }
            }
        }
    }
}

// ---------- a_src/a_dst from bf16 h_bt (pre-scaled by log2(e)) ----------
__global__ __launch_bounds__(256) void a_kernel(const unsigned short* __restrict__ h_bt,
                                                const float* __restrict__ w_src,
                                                const float* __restrict__ w_dst,
                                                float* __restrict__ a_src, float* __restrict__ a_dst) {
    __shared__ unsigned short ht[96 * 72];
    __shared__ float ws_s[96], wd_s[96];
    __shared__ float pps[4][64], ppd[4][64];
    int bh = blockIdx.x >> 4;
    int n0 = (blockIdx.x & 15) * 64;
    int head = bh & 7;
    int t = threadIdx.x;
    if (t < 96) { ws_s[t] = w_src[head * 96 + t]; wd_s[t] = w_dst[head * 96 + t]; }
    for (int f = t; f < 768; f += 256) {
        int row = f >> 3, c8 = (f & 7) * 8;
        *(short8*)(ht + row * 72 + c8) = *(const short8*)(h_bt + ((size_t)bh * 96 + row) * NN + n0 + c8);
    }
    __syncthreads();
    int n = t & 63, part = t >> 6;
    float ps = 0.f, pd = 0.f;
    #pragma unroll
    for (int oo = 0; oo < 24; ++oo) {
        int o = part * 24 + oo;
        float th = tanh_fast(bf2f(ht[o * 72 + n]));
        ps += th * ws_s[o];
        pd += th * wd_s[o];
    }
    pps[part][n] = ps; ppd[part][n] = pd;
    __syncthreads();
    if (t < 64) {
        float s = pps[0][t] + pps[1][t] + pps[2][t] + pps[3][t];
        float d = ppd[0][t] + ppd[1][t] + ppd[2][t] + ppd[3][t];
        a_src[bh * 1024 + n0 + t] = s * 1.44269504f;    // log2(e) folded for exp2
        a_dst[bh * 1024 + n0 + t] = d * 1.44269504f;
    }
}

// ---------- attention + fused epilogue ----------
// 512 threads, i-tile 128 (one i-16-row per wave), bitmask adj (2 dwords/thread/iter),
// register-direct E build, DMA double-buffered hs, one barrier per j-iter.
__global__ __launch_bounds__(512) void attn_kernel(
        const unsigned short* __restrict__ h_bt, const unsigned int* __restrict__ abits,
        const float* __restrict__ a_src_g, const float* __restrict__ a_dst_g,
        const unsigned short* __restrict__ gate, const unsigned short* __restrict__ Xb,
        const float* __restrict__ bias, float* __restrict__ out) {
    __shared__ __align__(16) unsigned short hs[2][96 * 64];
    __shared__ __align__(16) float adst[1024];
    __shared__ float bias_s[96];
    int blk = blockIdx.x;
    int bh = blk >> 3, i0 = (blk & 7) * 128, b = bh >> 3, hh = bh & 7;
    int t = threadIdx.x;
    int w = t >> 6, lane = t & 63, l15 = t & 15, quad = lane >> 4;
    if (t < 256) *(f32x4*)(adst + t * 4) = *(const f32x4*)(a_dst_g + bh * 1024 + t * 4);
    if (t < 96) bias_s[t] = bias[t];
    int irow = i0 + w * 16 + l15;
    float si = a_src_g[bh * 1024 + irow];
    const unsigned short* hhp = h_bt + (size_t)bh * 96 * NN;
    // DMA tile 0 into hs[0] (waves 0..5, 2 chunks each)
    if (w < 6) {
        #pragma unroll
        for (int cc = 0; cc < 2; ++cc) {
            int u0 = (w * 2 + cc) * 64;
            int p = u0 + lane;
            int r = p >> 3, qs = p & 7, qb = qs ^ (r & 7);
            gload_lds16(hhp + (size_t)r * NN + qb * 8, (char*)&hs[0][0] + (size_t)u0 * 16);
        }
    }
    const unsigned int* mrow = abits + ((size_t)b * NN + irow) * 32;
    uint2 mw = *(const uint2*)(mrow);           // mask dwords for j in [0,64)
    f32x4 acc[7] = {};
    short8 ones = {};
    if (l15 == 0) {
        #pragma unroll
        for (int u = 0; u < 8; ++u) ones[u] = (short)0x3F80;   // bf16 1.0
    }
    __syncthreads();
    for (int j0 = 0; j0 < 1024; j0 += 64) {
        int cur = (j0 >> 6) & 1;
        int jn = j0 + 64;
        // DMA next h tile into the other buffer (drained by the end-of-iter barrier)
        if (jn < 1024 && w < 6) {
            #pragma unroll
            for (int cc = 0; cc < 2; ++cc) {
                int u0 = (w * 2 + cc) * 64;
                int p = u0 + lane;
                int r = p >> 3, qs = p & 7, qb = qs ^ (r & 7);
                gload_lds16(hhp + (size_t)r * NN + jn + qb * 8, (char*)&hs[cur ^ 1][0] + (size_t)u0 * 16);
            }
        }
        // build A fragments in-register: lane owns E[i=w*16+l15][j=ks*32+quad*8+u]
        short8 af[2];
        unsigned int mws[2] = {mw.x, mw.y};
        #pragma unroll
        for (int ks = 0; ks < 2; ++ks) {
            unsigned int byte = (mws[ks] >> (quad * 8)) & 0xFFu;
            f32x4 d0 = *(const f32x4*)(&adst[j0 + ks * 32 + quad * 8]);
            f32x4 d1 = *(const f32x4*)(&adst[j0 + ks * 32 + quad * 8 + 4]);
            float dv[8] = {d0[0], d0[1], d0[2], d0[3], d1[0], d1[1], d1[2], d1[3]};
            float ev[8];
            #pragma unroll
            for (int u = 0; u < 8; ++u) {
                float s = si + dv[u];
                float l = fmaxf(s, 0.2f * s);
                float e = __builtin_amdgcn_exp2f(l);
                ev[u] = ((byte >> u) & 1u) ? e : 0.f;
            }
            union { unsigned int u4[4]; short8 s8; } pk;
            #pragma unroll
            for (int p2 = 0; p2 < 4; ++p2) {
                unsigned int u0b = __builtin_bit_cast(unsigned int, ev[2 * p2]) + 0x8000u;
                unsigned int u1b = __builtin_bit_cast(unsigned int, ev[2 * p2 + 1]) + 0x8000u;
                pk.u4[p2] = __builtin_amdgcn_perm(u1b, u0b, 0x07060302);
            }
            af[ks] = pk.s8;
        }
        // prefetch mask for next iter
        if (jn < 1024) mw = *(const uint2*)(mrow + (jn >> 5));
        // MFMA on current buffer
        #pragma unroll
        for (int ks = 0; ks < 2; ++ks) {
            #pragma unroll
            for (int nt = 0; nt < 6; ++nt) {
                int r = nt * 16 + l15;
                int qs = (ks * 4 + quad) ^ (r & 7);
                short8 bfr = *(const short8*)(&hs[cur][(size_t)(r * 8 + qs) * 8]);
                acc[nt] = __builtin_amdgcn_mfma_f32_16x16x32_bf16(af[ks], bfr, acc[nt], 0, 0, 0);
            }
            acc[6] = __builtin_amdgcn_mfma_f32_16x16x32_bf16(af[ks], ones, acc[6], 0, 0, 0);
        }
        __syncthreads();
    }
    // fused epilogue: bias + elu + precomputed f16 gate + bf16 x + blend -> out
    int rowq = i0 + w * 16 + quad * 4;
    #pragma unroll
    for (int reg = 0; reg < 4; ++reg) {
        float ssum = __shfl(acc[6][reg], (lane & 48));    // ones-column (n=0) holds row sum
        float inv = (ssum > 0.f) ? __builtin_amdgcn_rcpf(ssum) : 0.f;
        int n = rowq + reg;
        size_t mrow_o = ((size_t)b * NN + n) * 768 + hh * 96;
        #pragma unroll
        for (int nt = 0; nt < 6; ++nt) {
            int cl = nt * 16 + l15;
            float v = acc[nt][reg] * inv + bias_s[cl];
            float e = (v > 0.f) ? v : (__builtin_amdgcn_exp2f(v * 1.44269504f) - 1.f);
            _Float16 gh = __builtin_bit_cast(_Float16, gate[mrow_o + cl]);
            float g = (float)gh;
            float x = bf2f(Xb[mrow_o + cl]);
            out[mrow_o + cl] = x + g * (e - x);
        }
    }
}

extern "C" void kernel_launch(void* const* d_in, const int* in_sizes, int n_in,
                              void* d_out, int out_size, void* d_ws, size_t ws_size,
                              hipStream_t stream) {
    const float* feat_in = (const float*)d_in[0];
    const float* adj     = (const float*)d_in[1];
    const float* W       = (const float*)d_in[2];
    const float* bbias   = (const float*)d_in[3];
    const float* w_src   = (const float*)d_in[4];
    const float* w_dst   = (const float*)d_in[5];
    const float* Hw      = (const float*)d_in[6];
    const float* Hb      = (const float*)d_in[7];
    float* out = (float*)d_out;
    char* base = (char*)d_ws;

    unsigned short* Xb    = (unsigned short*)(base);                 // 12,582,912 B
    unsigned short* BcatT = (unsigned short*)(base + 12582912);      //  2,359,296 B
    unsigned short* h_bt  = (unsigned short*)(base + 14942208);      // 12,582,912 B
    unsigned short* gate  = (unsigned short*)(base + 27525120);      // 12,582,912 B (f16)
    float* a_src = (float*)(base + 40108032);                        //    262,144 B
    float* a_dst = (float*)(base + 40370176);                        //    262,144 B
    unsigned int* abits = (unsigned int*)(base + 40632320);          //  1,048,576 B (end ~41.7 MB)

    xb_kernel<<<(M_ROWS * IN_DIM / 8) / 256, 256, 0, stream>>>(feat_in, Xb);
    pack_w_kernel<<<(768 * IN_DIM) / 256, 256, 0, stream>>>(W, BcatT);
    pack_hw_kernel<<<(768 * IN_DIM) / 256, 256, 0, stream>>>(Hw, BcatT);
    pack_abits_kernel<<<(BATCH * NN * NN / 32) / 256, 256, 0, stream>>>(adj, abits);
    gemm1_kernel<<<dim3(M_ROWS / 128, NCOLS / 128), 256, 0, stream>>>(Xb, BcatT, Hb, h_bt, gate);
    a_kernel<<<64 * 16, 256, 0, stream>>>(h_bt, w_src, w_dst, a_src, a_dst);
    attn_kernel<<<64 * 8, 512, 0, stream>>>(h_bt, abits, a_src, a_dst, gate, Xb, bbias, out);
}

// Round 9
// 187.673 us; speedup vs baseline: 1.0712x; 1.0173x over previous
//
#include <hip/hip_runtime.h>
#include <cstddef>

#define BATCH 8
#define NN 1024
#define IN_DIM 768
#define OUT_DIM 96
#define HEADS 8
#define M_ROWS 8192
#define NCOLS 1536

typedef __attribute__((ext_vector_type(8))) short short8;
typedef __attribute__((ext_vector_type(4))) float f32x4;
typedef __attribute__((ext_vector_type(4))) unsigned short ushort4v;
typedef _Float16 half8 __attribute__((ext_vector_type(8)));

typedef __attribute__((address_space(1))) void gvoid_t;
typedef __attribute__((address_space(3))) void lvoid_t;

// async global->LDS, 16B per lane; lds dest = wave-uniform base + lane*16
__device__ __forceinline__ void gload_lds16(const void* g, void* l) {
    __builtin_amdgcn_global_load_lds((gvoid_t*)(unsigned long long)g,
                                     (lvoid_t*)(unsigned int)(unsigned long long)l,
                                     16, 0, 0);
}

// pack two f32 -> one dword of two f16 (RTZ hardware op)
__device__ __forceinline__ unsigned int pkrtz(float a, float b) {
    return __builtin_bit_cast(unsigned int, __builtin_amdgcn_cvt_pkrtz(a, b));
}
__device__ __forceinline__ unsigned short f2h(float x) {
    _Float16 h = (_Float16)x;
    return __builtin_bit_cast(unsigned short, h);
}
__device__ __forceinline__ float h2f(unsigned short u) {
    return (float)__builtin_bit_cast(_Float16, u);
}
__device__ __forceinline__ float tanh_fast(float x) {
    return 1.f - 2.f / (__expf(2.f * x) + 1.f);
}
__device__ __forceinline__ f32x4 mfma16(short8 a, short8 b, f32x4 c) {
    return __builtin_amdgcn_mfma_f32_16x16x32_f16(
        __builtin_bit_cast(half8, a), __builtin_bit_cast(half8, b), c, 0, 0, 0);
}

// ---------- fused prep: xb + pack_w + pack_hw + pack_abits ----------
// Sections: [0,3072) Xb  [3072,5376) W  [5376,7680) Hw  [7680,8704) abits
__global__ __launch_bounds__(256) void prep_kernel(
        const float* __restrict__ feat_in, const float* __restrict__ W,
        const float* __restrict__ Hw, const float* __restrict__ adj,
        unsigned short* __restrict__ Xb, unsigned short* __restrict__ BT,
        unsigned int* __restrict__ abits) {
    int blk = blockIdx.x;
    int t = threadIdx.x;
    if (blk < 3072) {                                 // feat_in f32 -> f16, 8/thread
        int idx = blk * 256 + t;
        const float4* p = (const float4*)(feat_in + (size_t)idx * 8);
        float4 a = p[0], b = p[1];
        union { unsigned int u4[4]; short8 s8; } pk;
        pk.u4[0] = pkrtz(a.x, a.y);
        pk.u4[1] = pkrtz(a.z, a.w);
        pk.u4[2] = pkrtz(b.x, b.y);
        pk.u4[3] = pkrtz(b.z, b.w);
        *(short8*)(Xb + (size_t)idx * 8) = pk.s8;
    } else if (blk < 5376) {                          // W[h][i][o] -> BT[c][i] f16
        int idx = (blk - 3072) * 256 + t;
        int c = idx / IN_DIM, i = idx % IN_DIM;
        int h = c / OUT_DIM, o = c % OUT_DIM;
        BT[(size_t)c * IN_DIM + i] = f2h(W[((size_t)h * IN_DIM + i) * OUT_DIM + o]);
    } else if (blk < 7680) {                          // Hw[c][i] -> BT[768+c][i] f16
        int idx = (blk - 5376) * 256 + t;
        int c = idx / IN_DIM, i = idx % IN_DIM;
        BT[(size_t)(768 + c) * IN_DIM + i] = f2h(Hw[(size_t)c * IN_DIM + i]);
    } else {                                          // adj -> 1-bit mask, 32/thread
        int idx = (blk - 7680) * 256 + t;
        const float4* p = (const float4*)(adj + (size_t)idx * 32);
        unsigned int m = 0;
        #pragma unroll
        for (int q = 0; q < 8; ++q) {
            float4 v = p[q];
            m |= (v.x != 0.f ? 1u : 0u) << (q * 4 + 0);
            m |= (v.y != 0.f ? 1u : 0u) << (q * 4 + 1);
            m |= (v.z != 0.f ? 1u : 0u) << (q * 4 + 2);
            m |= (v.w != 0.f ? 1u : 0u) << (q * 4 + 3);
        }
        abits[idx] = m;
    }
}

// ---------- GEMM1: Xb[8192,768] @ BT^T -> h_bt (f16 [bh][o][n]) + gate (f16) ----------
__global__ __launch_bounds__(256) void gemm1_kernel(
        const unsigned short* __restrict__ Xb, const unsigned short* __restrict__ BT,
        const float* __restrict__ Hb,
        unsigned short* __restrict__ h_bt, unsigned short* __restrict__ gate) {
    __shared__ __align__(16) unsigned short As[128 * 64];
    __shared__ __align__(16) unsigned short Bs[128 * 64];
    __shared__ float hbs[128];
    int m0 = blockIdx.x * 128;
    int c0 = blockIdx.y * 128;
    int t = threadIdx.x;
    int w = t >> 6, lane = t & 63, l15 = t & 15, quad = lane >> 4;
    if (c0 >= 768 && t < 128) hbs[t] = Hb[c0 - 768 + t];
    f32x4 acc[2][8] = {};
    for (int k0 = 0; k0 < IN_DIM; k0 += 64) {
        __syncthreads();
        #pragma unroll
        for (int cc = 0; cc < 4; ++cc) {
            int base64 = (w * 4 + cc) * 64;          // wave-uniform chunk base
            int p = base64 + lane;
            int r = p >> 3, qs = p & 7;
            int qb = qs ^ (r & 7);                   // inverse of read-side swizzle
            gload_lds16(Xb + (size_t)(m0 + r) * IN_DIM + k0 + qb * 8, As + base64 * 8);
            gload_lds16(BT + (size_t)(c0 + r) * IN_DIM + k0 + qb * 8, Bs + base64 * 8);
        }
        __syncthreads();
        #pragma unroll
        for (int ks = 0; ks < 2; ++ks) {
            short8 af[2], bfr[8];
            #pragma unroll
            for (int mt = 0; mt < 2; ++mt) {
                int r = w * 32 + mt * 16 + l15;
                int cb = (ks * 4 + quad) ^ (r & 7);
                af[mt] = *(const short8*)(As + r * 64 + cb * 8);
            }
            #pragma unroll
            for (int nt = 0; nt < 8; ++nt) {
                int r = nt * 16 + l15;
                int cb = (ks * 4 + quad) ^ (r & 7);
                bfr[nt] = *(const short8*)(Bs + r * 64 + cb * 8);
            }
            #pragma unroll
            for (int mt = 0; mt < 2; ++mt)
                #pragma unroll
                for (int nt = 0; nt < 8; ++nt)
                    acc[mt][nt] = mfma16(af[mt], bfr[nt], acc[mt][nt]);
        }
    }
    int b = m0 >> 10;
    #pragma unroll
    for (int mt = 0; mt < 2; ++mt) {
        int rowbase = m0 + w * 32 + mt * 16 + quad * 4;
        int nbase = rowbase & 1023;
        #pragma unroll
        for (int nt = 0; nt < 8; ++nt) {
            int c = c0 + nt * 16 + l15;
            if (c < 768) {
                int hh = c / OUT_DIM, o = c % OUT_DIM;
                union { unsigned int u2[2]; ushort4v u4; } pk;
                pk.u2[0] = pkrtz(acc[mt][nt][0], acc[mt][nt][1]);
                pk.u2[1] = pkrtz(acc[mt][nt][2], acc[mt][nt][3]);
                *(ushort4v*)(h_bt + ((size_t)(b * 8 + hh) * OUT_DIM + o) * NN + nbase) = pk.u4;
            } else {
                int cl = nt * 16 + l15;
                int cg = c - 768;
                #pragma unroll
                for (int reg = 0; reg < 4; ++reg) {
                    float z = acc[mt][nt][reg] + hbs[cl];
                    float g = __builtin_amdgcn_rcpf(1.f + __builtin_amdgcn_exp2f(-1.44269504f * z));
                    gate[(size_t)(rowbase + reg) * 768 + cg] = f2h(g);
                }
            }
        }
    }
}

// ---------- a_src/a_dst from f16 h_bt (pre-scaled by log2(e)) ----------
__global__ __launch_bounds__(256) void a_kernel(const unsigned short* __restrict__ h_bt,
                                                const float* __restrict__ w_src,
                                                const float* __restrict__ w_dst,
                                                float* __restrict__ a_src, float* __restrict__ a_dst) {
    __shared__ unsigned short ht[96 * 72];
    __shared__ float ws_s[96], wd_s[96];
    __shared__ float pps[4][64], ppd[4][64];
    int bh = blockIdx.x >> 4;
    int n0 = (blockIdx.x & 15) * 64;
    int head = bh & 7;
    int t = threadIdx.x;
    if (t < 96) { ws_s[t] = w_src[head * 96 + t]; wd_s[t] = w_dst[head * 96 + t]; }
    for (int f = t; f < 768; f += 256) {
        int row = f >> 3, c8 = (f & 7) * 8;
        *(short8*)(ht + row * 72 + c8) = *(const short8*)(h_bt + ((size_t)bh * 96 + row) * NN + n0 + c8);
    }
    __syncthreads();
    int n = t & 63, part = t >> 6;
    float ps = 0.f, pd = 0.f;
    #pragma unroll
    for (int oo = 0; oo < 24; ++oo) {
        int o = part * 24 + oo;
        float th = tanh_fast(h2f(ht[o * 72 + n]));
        ps += th * ws_s[o];
        pd += th * wd_s[o];
    }
    pps[part][n] = ps; ppd[part][n] = pd;
    __syncthreads();
    if (t < 64) {
        float s = pps[0][t] + pps[1][t] + pps[2][t] + pps[3][t];
        float d = ppd[0][t] + ppd[1][t] + ppd[2][t] + ppd[3][t];
        a_src[bh * 1024 + n0 + t] = s * 1.44269504f;    // log2(e) folded for exp2
        a_dst[bh * 1024 + n0 + t] = d * 1.44269504f;
    }
}

// ---------- attention + fused epilogue (f16 E/h, cvt_pkrtz fragment pack) ----------
__global__ __launch_bounds__(512) void attn_kernel(
        const unsigned short* __restrict__ h_bt, const unsigned int* __restrict__ abits,
        const float* __restrict__ a_src_g, const float* __restrict__ a_dst_g,
        const unsigned short* __restrict__ gate, const unsigned short* __restrict__ Xb,
        const float* __restrict__ bias, float* __restrict__ out) {
    __shared__ __align__(16) unsigned short hs[2][96 * 64];
    __shared__ __align__(16) float adst[1024];
    __shared__ float bias_s[96];
    int blk = blockIdx.x;
    int bh = blk >> 3, i0 = (blk & 7) * 128, b = bh >> 3, hh = bh & 7;
    int t = threadIdx.x;
    int w = t >> 6, lane = t & 63, l15 = t & 15, quad = lane >> 4;
    if (t < 256) *(f32x4*)(adst + t * 4) = *(const f32x4*)(a_dst_g + bh * 1024 + t * 4);
    if (t < 96) bias_s[t] = bias[t];
    int irow = i0 + w * 16 + l15;
    float si = a_src_g[bh * 1024 + irow];
    const unsigned short* hhp = h_bt + (size_t)bh * 96 * NN;
    // DMA tile 0 into hs[0] (waves 0..5, 2 chunks each)
    if (w < 6) {
        #pragma unroll
        for (int cc = 0; cc < 2; ++cc) {
            int u0 = (w * 2 + cc) * 64;
            int p = u0 + lane;
            int r = p >> 3, qs = p & 7, qb = qs ^ (r & 7);
            gload_lds16(hhp + (size_t)r * NN + qb * 8, (char*)&hs[0][0] + (size_t)u0 * 16);
        }
    }
    const unsigned int* mrow = abits + ((size_t)b * NN + irow) * 32;
    uint2 mw = *(const uint2*)(mrow);           // mask dwords for j in [0,64)
    f32x4 acc[7] = {};
    short8 ones = {};
    if (l15 == 0) {
        #pragma unroll
        for (int u = 0; u < 8; ++u) ones[u] = (short)0x3C00;   // f16 1.0
    }
    __syncthreads();
    for (int j0 = 0; j0 < 1024; j0 += 64) {
        int cur = (j0 >> 6) & 1;
        int jn = j0 + 64;
        // DMA next h tile into the other buffer (drained by the end-of-iter barrier)
        if (jn < 1024 && w < 6) {
            #pragma unroll
            for (int cc = 0; cc < 2; ++cc) {
                int u0 = (w * 2 + cc) * 64;
                int p = u0 + lane;
                int r = p >> 3, qs = p & 7, qb = qs ^ (r & 7);
                gload_lds16(hhp + (size_t)r * NN + jn + qb * 8, (char*)&hs[cur ^ 1][0] + (size_t)u0 * 16);
            }
        }
        // build A fragments in-register: lane owns E[i=w*16+l15][j=ks*32+quad*8+u]
        short8 af[2];
        unsigned int mws[2] = {mw.x, mw.y};
        #pragma unroll
        for (int ks = 0; ks < 2; ++ks) {
            unsigned int byte = (mws[ks] >> (quad * 8)) & 0xFFu;
            f32x4 d0 = *(const f32x4*)(&adst[j0 + ks * 32 + quad * 8]);
            f32x4 d1 = *(const f32x4*)(&adst[j0 + ks * 32 + quad * 8 + 4]);
            float dv[8] = {d0[0], d0[1], d0[2], d0[3], d1[0], d1[1], d1[2], d1[3]};
            float ev[8];
            #pragma unroll
            for (int u = 0; u < 8; ++u) {
                float s = si + dv[u];
                float l = fmaxf(s, 0.2f * s);
                float e = __builtin_amdgcn_exp2f(l);
                ev[u] = ((byte >> u) & 1u) ? e : 0.f;
            }
            union { unsigned int u4[4]; short8 s8; } pk;
            pk.u4[0] = pkrtz(ev[0], ev[1]);
            pk.u4[1] = pkrtz(ev[2], ev[3]);
            pk.u4[2] = pkrtz(ev[4], ev[5]);
            pk.u4[3] = pkrtz(ev[6], ev[7]);
            af[ks] = pk.s8;
        }
        // prefetch mask for next iter
        if (jn < 1024) mw = *(const uint2*)(mrow + (jn >> 5));
        // MFMA on current buffer
        #pragma unroll
        for (int ks = 0; ks < 2; ++ks) {
            #pragma unroll
            for (int nt = 0; nt < 6; ++nt) {
                int r = nt * 16 + l15;
                int qs = (ks * 4 + quad) ^ (r & 7);
                short8 bfr = *(const short8*)(&hs[cur][(size_t)(r * 8 + qs) * 8]);
                acc[nt] = mfma16(af[ks], bfr, acc[nt]);
            }
            acc[6] = mfma16(af[ks], ones, acc[6]);
        }
        __syncthreads();
    }
    // fused epilogue: bias + elu + precomputed f16 gate + f16 x + blend -> out
    int rowq = i0 + w * 16 + quad * 4;
    #pragma unroll
    for (int reg = 0; reg < 4; ++reg) {
        float ssum = __shfl(acc[6][reg], (lane & 48));    // ones-column (n=0) holds row sum
        float inv = (ssum > 0.f) ? __builtin_amdgcn_rcpf(ssum) : 0.f;
        int n = rowq + reg;
        size_t mrow_o = ((size_t)b * NN + n) * 768 + hh * 96;
        #pragma unroll
        for (int nt = 0; nt < 6; ++nt) {
            int cl = nt * 16 + l15;
            float v = acc[nt][reg] * inv + bias_s[cl];
            float e = (v > 0.f) ? v : (__builtin_amdgcn_exp2f(v * 1.44269504f) - 1.f);
            float g = h2f(gate[mrow_o + cl]);
            float x = h2f(Xb[mrow_o + cl]);
            out[mrow_o + cl] = x + g * (e - x);
        }
    }
}

extern "C" void kernel_launch(void* const* d_in, const int* in_sizes, int n_in,
                              void* d_out, int out_size, void* d_ws, size_t ws_size,
                              hipStream_t stream) {
    const float* feat_in = (const float*)d_in[0];
    const float* adj     = (const float*)d_in[1];
    const float* W       = (const float*)d_in[2];
    const float* bbias   = (const float*)d_in[3];
    const float* w_src   = (const float*)d_in[4];
    const float* w_dst   = (const float*)d_in[5];
    const float* Hw      = (const float*)d_in[6];
    const float* Hb      = (const float*)d_in[7];
    float* out = (float*)d_out;
    char* base = (char*)d_ws;

    unsigned short* Xb    = (unsigned short*)(base);                 // 12,582,912 B (f16)
    unsigned short* BcatT = (unsigned short*)(base + 12582912);      //  2,359,296 B (f16)
    unsigned short* h_bt  = (unsigned short*)(base + 14942208);      // 12,582,912 B (f16)
    unsigned short* gate  = (unsigned short*)(base + 27525120);      // 12,582,912 B (f16)
    float* a_src = (float*)(base + 40108032);                        //    262,144 B
    float* a_dst = (float*)(base + 40370176);                        //    262,144 B
    unsigned int* abits = (unsigned int*)(base + 40632320);          //  1,048,576 B (end ~41.7 MB)

    prep_kernel<<<8704, 256, 0, stream>>>(feat_in, W, Hw, adj, Xb, BcatT, abits);
    gemm1_kernel<<<dim3(M_ROWS / 128, NCOLS / 128), 256, 0, stream>>>(Xb, BcatT, Hb, h_bt, gate);
    a_kernel<<<64 * 16, 256, 0, stream>>>(h_bt, w_src, w_dst, a_src, a_dst);
    attn_kernel<<<64 * 8, 512, 0, stream>>>(h_bt, abits, a_src, a_dst, gate, Xb, bbias, out);
}

// Round 10
// 186.233 us; speedup vs baseline: 1.0795x; 1.0077x over previous
//
#include <hip/hip_runtime.h>
#include <cstddef>

#define BATCH 8
#define NN 1024
#define IN_DIM 768
#define OUT_DIM 96
#define HEADS 8
#define M_ROWS 8192
#define NCOLS 1536

typedef __attribute__((ext_vector_type(8))) short short8;
typedef __attribute__((ext_vector_type(4))) float f32x4;
typedef __attribute__((ext_vector_type(4))) unsigned short ushort4v;
typedef _Float16 half8 __attribute__((ext_vector_type(8)));

typedef __attribute__((address_space(1))) void gvoid_t;
typedef __attribute__((address_space(3))) void lvoid_t;

// async global->LDS, 16B per lane; lds dest = wave-uniform base + lane*16
__device__ __forceinline__ void gload_lds16(const void* g, void* l) {
    __builtin_amdgcn_global_load_lds((gvoid_t*)(unsigned long long)g,
                                     (lvoid_t*)(unsigned int)(unsigned long long)l,
                                     16, 0, 0);
}

// pack two f32 -> one dword of two f16 (RTZ hardware op)
__device__ __forceinline__ unsigned int pkrtz(float a, float b) {
    return __builtin_bit_cast(unsigned int, __builtin_amdgcn_cvt_pkrtz(a, b));
}
__device__ __forceinline__ unsigned short f2h(float x) {
    _Float16 h = (_Float16)x;
    return __builtin_bit_cast(unsigned short, h);
}
__device__ __forceinline__ float h2f(unsigned short u) {
    return (float)__builtin_bit_cast(_Float16, u);
}
__device__ __forceinline__ float tanh_fast(float x) {
    return 1.f - 2.f / (__expf(2.f * x) + 1.f);
}
__device__ __forceinline__ f32x4 mfma16(short8 a, short8 b, f32x4 c) {
    return __builtin_amdgcn_mfma_f32_16x16x32_f16(
        __builtin_bit_cast(half8, a), __builtin_bit_cast(half8, b), c, 0, 0, 0);
}

// ---------- fused prep: xb + pack_w + pack_hw + pack_abits + zero a_src/a_dst ----------
// Sections: [0,3072) Xb  [3072,5376) W  [5376,7680) Hw  [7680,8704) abits  [8704,8768) zeros
__global__ __launch_bounds__(256) void prep_kernel(
        const float* __restrict__ feat_in, const float* __restrict__ W,
        const float* __restrict__ Hw, const float* __restrict__ adj,
        unsigned short* __restrict__ Xb, unsigned short* __restrict__ BT,
        unsigned int* __restrict__ abits, float* __restrict__ a_zero) {
    int blk = blockIdx.x;
    int t = threadIdx.x;
    if (blk < 3072) {                                 // feat_in f32 -> f16, 8/thread
        int idx = blk * 256 + t;
        const float4* p = (const float4*)(feat_in + (size_t)idx * 8);
        float4 a = p[0], b = p[1];
        union { unsigned int u4[4]; short8 s8; } pk;
        pk.u4[0] = pkrtz(a.x, a.y);
        pk.u4[1] = pkrtz(a.z, a.w);
        pk.u4[2] = pkrtz(b.x, b.y);
        pk.u4[3] = pkrtz(b.z, b.w);
        *(short8*)(Xb + (size_t)idx * 8) = pk.s8;
    } else if (blk < 5376) {                          // W[h][i][o] -> BT[c][i] f16
        int idx = (blk - 3072) * 256 + t;
        int c = idx / IN_DIM, i = idx % IN_DIM;
        int h = c / OUT_DIM, o = c % OUT_DIM;
        BT[(size_t)c * IN_DIM + i] = f2h(W[((size_t)h * IN_DIM + i) * OUT_DIM + o]);
    } else if (blk < 7680) {                          // Hw[c][i] -> BT[768+c][i] f16
        int idx = (blk - 5376) * 256 + t;
        int c = idx / IN_DIM, i = idx % IN_DIM;
        BT[(size_t)(768 + c) * IN_DIM + i] = f2h(Hw[(size_t)c * IN_DIM + i]);
    } else if (blk < 8704) {                          // adj -> 1-bit mask, 32/thread
        int idx = (blk - 7680) * 256 + t;
        const float4* p = (const float4*)(adj + (size_t)idx * 32);
        unsigned int m = 0;
        #pragma unroll
        for (int q = 0; q < 8; ++q) {
            float4 v = p[q];
            m |= (v.x != 0.f ? 1u : 0u) << (q * 4 + 0);
            m |= (v.y != 0.f ? 1u : 0u) << (q * 4 + 1);
            m |= (v.z != 0.f ? 1u : 0u) << (q * 4 + 2);
            m |= (v.w != 0.f ? 1u : 0u) << (q * 4 + 3);
        }
        abits[idx] = m;
    } else {                                          // zero a_src+a_dst (contiguous 1 MB)
        int idx = (blk - 8704) * 256 + t;
        f32x4 z = {0.f, 0.f, 0.f, 0.f};
        *(f32x4*)(a_zero + (size_t)idx * 8) = z;
        *(f32x4*)(a_zero + (size_t)idx * 8 + 4) = z;
    }
}

// ---------- GEMM1: Xb @ BT^T -> h_bt (f16 [bh][o][n]) + gate (f16) + a_src/a_dst partials ----------
__global__ __launch_bounds__(256) void gemm1_kernel(
        const unsigned short* __restrict__ Xb, const unsigned short* __restrict__ BT,
        const float* __restrict__ Hb, const float* __restrict__ w_src,
        const float* __restrict__ w_dst,
        unsigned short* __restrict__ h_bt, unsigned short* __restrict__ gate,
        float* __restrict__ a_src, float* __restrict__ a_dst) {
    __shared__ __align__(16) unsigned short As[128 * 64];
    __shared__ __align__(16) unsigned short Bs[128 * 64];
    __shared__ float hbs[128];
    __shared__ float ws_s[128], wd_s[128];
    int m0 = blockIdx.x * 128;
    int c0 = blockIdx.y * 128;
    int t = threadIdx.x;
    int w = t >> 6, lane = t & 63, l15 = t & 15, quad = lane >> 4;
    if (c0 >= 768) {
        if (t < 128) hbs[t] = Hb[c0 - 768 + t];
    } else {
        if (t < 128) {
            int c = c0 + t;
            int hd = c / OUT_DIM, o = c % OUT_DIM;
            ws_s[t] = w_src[hd * OUT_DIM + o];
            wd_s[t] = w_dst[hd * OUT_DIM + o];
        }
    }
    f32x4 acc[2][8] = {};
    for (int k0 = 0; k0 < IN_DIM; k0 += 64) {
        __syncthreads();
        #pragma unroll
        for (int cc = 0; cc < 4; ++cc) {
            int base64 = (w * 4 + cc) * 64;          // wave-uniform chunk base
            int p = base64 + lane;
            int r = p >> 3, qs = p & 7;
            int qb = qs ^ (r & 7);                   // inverse of read-side swizzle
            gload_lds16(Xb + (size_t)(m0 + r) * IN_DIM + k0 + qb * 8, As + base64 * 8);
            gload_lds16(BT + (size_t)(c0 + r) * IN_DIM + k0 + qb * 8, Bs + base64 * 8);
        }
        __syncthreads();
        #pragma unroll
        for (int ks = 0; ks < 2; ++ks) {
            short8 af[2], bfr[8];
            #pragma unroll
            for (int mt = 0; mt < 2; ++mt) {
                int r = w * 32 + mt * 16 + l15;
                int cb = (ks * 4 + quad) ^ (r & 7);
                af[mt] = *(const short8*)(As + r * 64 + cb * 8);
            }
            #pragma unroll
            for (int nt = 0; nt < 8; ++nt) {
                int r = nt * 16 + l15;
                int cb = (ks * 4 + quad) ^ (r & 7);
                bfr[nt] = *(const short8*)(Bs + r * 64 + cb * 8);
            }
            #pragma unroll
            for (int mt = 0; mt < 2; ++mt)
                #pragma unroll
                for (int nt = 0; nt < 8; ++nt)
                    acc[mt][nt] = mfma16(af[mt], bfr[nt], acc[mt][nt]);
        }
    }
    int b = m0 >> 10;
    if (c0 < 768) {
        int split = (c0 / 96 + 1) * 96 - c0;         // cols belonging to lower head
        int headlo = c0 / 96;
        #pragma unroll
        for (int mt = 0; mt < 2; ++mt) {
            int rowbase = m0 + w * 32 + mt * 16 + quad * 4;
            int nbase = rowbase & 1023;
            // h store (f16, [bh][o][n])
            #pragma unroll
            for (int nt = 0; nt < 8; ++nt) {
                int c = c0 + nt * 16 + l15;
                int hh = c / OUT_DIM, o = c % OUT_DIM;
                union { unsigned int u2[2]; ushort4v u4; } pk;
                pk.u2[0] = pkrtz(acc[mt][nt][0], acc[mt][nt][1]);
                pk.u2[1] = pkrtz(acc[mt][nt][2], acc[mt][nt][3]);
                *(ushort4v*)(h_bt + ((size_t)(b * 8 + hh) * OUT_DIM + o) * NN + nbase) = pk.u4;
            }
            // a_src/a_dst partials: tanh(h)·w, split by head, reduce over l15, atomic
            #pragma unroll
            for (int reg = 0; reg < 4; ++reg) {
                float psA = 0.f, pdA = 0.f, psB = 0.f, pdB = 0.f;
                #pragma unroll
                for (int nt = 0; nt < 8; ++nt) {
                    int cl = nt * 16 + l15;
                    float th = tanh_fast(acc[mt][nt][reg]);
                    float s = th * ws_s[cl], d = th * wd_s[cl];
                    if (cl < split) { psA += s; pdA += d; }
                    else            { psB += s; pdB += d; }
                }
                #pragma unroll
                for (int mk = 1; mk <= 8; mk <<= 1) {
                    psA += __shfl_xor(psA, mk); pdA += __shfl_xor(pdA, mk);
                    psB += __shfl_xor(psB, mk); pdB += __shfl_xor(pdB, mk);
                }
                if (l15 == 0) {
                    int n2 = nbase + reg;
                    int ilo = (b * 8 + headlo) * 1024 + n2;
                    atomicAdd(&a_src[ilo], psA * 1.44269504f);
                    atomicAdd(&a_dst[ilo], pdA * 1.44269504f);
                    atomicAdd(&a_src[ilo + 1024], psB * 1.44269504f);
                    atomicAdd(&a_dst[ilo + 1024], pdB * 1.44269504f);
                }
            }
        }
    } else {
        #pragma unroll
        for (int mt = 0; mt < 2; ++mt) {
            int rowbase = m0 + w * 32 + mt * 16 + quad * 4;
            #pragma unroll
            for (int nt = 0; nt < 8; ++nt) {
                int cl = nt * 16 + l15;
                int cg = c0 - 768 + cl;
                #pragma unroll
                for (int reg = 0; reg < 4; ++reg) {
                    float z = acc[mt][nt][reg] + hbs[cl];
                    float g = __builtin_amdgcn_rcpf(1.f + __builtin_amdgcn_exp2f(-1.44269504f * z));
                    gate[(size_t)(rowbase + reg) * 768 + cg] = f2h(g);
                }
            }
        }
    }
}

// ---------- attention + fused epilogue (XCD-swizzled block mapping) ----------
__global__ __launch_bounds__(512) void attn_kernel(
        const unsigned short* __restrict__ h_bt, const unsigned int* __restrict__ abits,
        const float* __restrict__ a_src_g, const float* __restrict__ a_dst_g,
        const unsigned short* __restrict__ gate, const unsigned short* __restrict__ Xb,
        const float* __restrict__ bias, float* __restrict__ out) {
    __shared__ __align__(16) unsigned short hs[2][96 * 64];
    __shared__ __align__(16) float adst[1024];
    __shared__ float bias_s[96];
    int blk = blockIdx.x;
    // XCD swizzle: all 8 i-tiles of one bh land on the same XCD (blk%8 = bh/8)
    int bh = (blk & 7) * 8 + ((blk >> 3) & 7);
    int i0 = (blk >> 6) * 128;
    int b = bh >> 3, hh = bh & 7;
    int t = threadIdx.x;
    int w = t >> 6, lane = t & 63, l15 = t & 15, quad = lane >> 4;
    if (t < 256) *(f32x4*)(adst + t * 4) = *(const f32x4*)(a_dst_g + bh * 1024 + t * 4);
    if (t < 96) bias_s[t] = bias[t];
    int irow = i0 + w * 16 + l15;
    float si = a_src_g[bh * 1024 + irow];
    const unsigned short* hhp = h_bt + (size_t)bh * 96 * NN;
    // DMA tile 0 into hs[0] (waves 0..5, 2 chunks each)
    if (w < 6) {
        #pragma unroll
        for (int cc = 0; cc < 2; ++cc) {
            int u0 = (w * 2 + cc) * 64;
            int p = u0 + lane;
            int r = p >> 3, qs = p & 7, qb = qs ^ (r & 7);
            gload_lds16(hhp + (size_t)r * NN + qb * 8, (char*)&hs[0][0] + (size_t)u0 * 16);
        }
    }
    const unsigned int* mrow = abits + ((size_t)b * NN + irow) * 32;
    uint2 mw = *(const uint2*)(mrow);           // mask dwords for j in [0,64)
    f32x4 acc[7] = {};
    short8 ones = {};
    if (l15 == 0) {
        #pragma unroll
        for (int u = 0; u < 8; ++u) ones[u] = (short)0x3C00;   // f16 1.0
    }
    __syncthreads();
    for (int j0 = 0; j0 < 1024; j0 += 64) {
        int cur = (j0 >> 6) & 1;
        int jn = j0 + 64;
        // DMA next h tile into the other buffer (drained by the end-of-iter barrier)
        if (jn < 1024 && w < 6) {
            #pragma unroll
            for (int cc = 0; cc < 2; ++cc) {
                int u0 = (w * 2 + cc) * 64;
                int p = u0 + lane;
                int r = p >> 3, qs = p & 7, qb = qs ^ (r & 7);
                gload_lds16(hhp + (size_t)r * NN + jn + qb * 8, (char*)&hs[cur ^ 1][0] + (size_t)u0 * 16);
            }
        }
        // build A fragments in-register: lane owns E[i=w*16+l15][j=ks*32+quad*8+u]
        short8 af[2];
        unsigned int mws[2] = {mw.x, mw.y};
        #pragma unroll
        for (int ks = 0; ks < 2; ++ks) {
            unsigned int byte = (mws[ks] >> (quad * 8)) & 0xFFu;
            f32x4 d0 = *(const f32x4*)(&adst[j0 + ks * 32 + quad * 8]);
            f32x4 d1 = *(const f32x4*)(&adst[j0 + ks * 32 + quad * 8 + 4]);
            float dv[8] = {d0[0], d0[1], d0[2], d0[3], d1[0], d1[1], d1[2], d1[3]};
            float ev[8];
            #pragma unroll
            for (int u = 0; u < 8; ++u) {
                float s = si + dv[u];
                float l = fmaxf(s, 0.2f * s);
                float e = __builtin_amdgcn_exp2f(l);
                ev[u] = ((byte >> u) & 1u) ? e : 0.f;
            }
            union { unsigned int u4[4]; short8 s8; } pk;
            pk.u4[0] = pkrtz(ev[0], ev[1]);
            pk.u4[1] = pkrtz(ev[2], ev[3]);
            pk.u4[2] = pkrtz(ev[4], ev[5]);
            pk.u4[3] = pkrtz(ev[6], ev[7]);
            af[ks] = pk.s8;
        }
        // prefetch mask for next iter
        if (jn < 1024) mw = *(const uint2*)(mrow + (jn >> 5));
        // MFMA on current buffer
        #pragma unroll
        for (int ks = 0; ks < 2; ++ks) {
            #pragma unroll
            for (int nt = 0; nt < 6; ++nt) {
                int r = nt * 16 + l15;
                int qs = (ks * 4 + quad) ^ (r & 7);
                short8 bfr = *(const short8*)(&hs[cur][(size_t)(r * 8 + qs) * 8]);
                acc[nt] = mfma16(af[ks], bfr, acc[nt]);
            }
            acc[6] = mfma16(af[ks], ones, acc[6]);
        }
        __syncthreads();
    }
    // fused epilogue: bias + elu + precomputed f16 gate + f16 x + blend -> out
    int rowq = i0 + w * 16 + quad * 4;
    #pragma unroll
    for (int reg = 0; reg < 4; ++reg) {
        float ssum = __shfl(acc[6][reg], (lane & 48));    // ones-column (n=0) holds row sum
        float inv = (ssum > 0.f) ? __builtin_amdgcn_rcpf(ssum) : 0.f;
        int n = rowq + reg;
        size_t mrow_o = ((size_t)b * NN + n) * 768 + hh * 96;
        #pragma unroll
        for (int nt = 0; nt < 6; ++nt) {
            int cl = nt * 16 + l15;
            float v = acc[nt][reg] * inv + bias_s[cl];
            float e = (v > 0.f) ? v : (__builtin_amdgcn_exp2f(v * 1.44269504f) - 1.f);
            float g = h2f(gate[mrow_o + cl]);
            float x = h2f(Xb[mrow_o + cl]);
            out[mrow_o + cl] = x + g * (e - x);
        }
    }
}

extern "C" void kernel_launch(void* const* d_in, const int* in_sizes, int n_in,
                              void* d_out, int out_size, void* d_ws, size_t ws_size,
                              hipStream_t stream) {
    const float* feat_in = (const float*)d_in[0];
    const float* adj     = (const float*)d_in[1];
    const float* W       = (const float*)d_in[2];
    const float* bbias   = (const float*)d_in[3];
    const float* w_src   = (const float*)d_in[4];
    const float* w_dst   = (const float*)d_in[5];
    const float* Hw      = (const float*)d_in[6];
    const float* Hb      = (const float*)d_in[7];
    float* out = (float*)d_out;
    char* base = (char*)d_ws;

    unsigned short* Xb    = (unsigned short*)(base);                 // 12,582,912 B (f16)
    unsigned short* BcatT = (unsigned short*)(base + 12582912);      //  2,359,296 B (f16)
    unsigned short* h_bt  = (unsigned short*)(base + 14942208);      // 12,582,912 B (f16)
    unsigned short* gate  = (unsigned short*)(base + 27525120);      // 12,582,912 B (f16)
    float* a_src = (float*)(base + 40108032);                        //    262,144 B
    float* a_dst = (float*)(base + 40370176);                        //    262,144 B (contiguous after a_src)
    unsigned int* abits = (unsigned int*)(base + 40632320);          //  1,048,576 B (end ~41.7 MB)

    prep_kernel<<<8768, 256, 0, stream>>>(feat_in, W, Hw, adj, Xb, BcatT, abits, a_src);
    gemm1_kernel<<<dim3(M_ROWS / 128, NCOLS / 128), 256, 0, stream>>>(
        Xb, BcatT, Hb, w_src, w_dst, h_bt, gate, a_src, a_dst);
    attn_kernel<<<64 * 8, 512, 0, stream>>>(h_bt, abits, a_src, a_dst, gate, Xb, bbias, out);
}